// Round 14
// baseline (220.976 us; speedup 1.0000x reference)
//
#include <hip/hip_runtime.h>
#include <math.h>

#define N_NODES 50000
#define N_EDGES 800000
#define F_IN    128
#define F_OUT   64
#define ALPHA   0.2f

#define NP      50176              // N_NODES padded to 196*256
#define NB      196                // scan blocks
#define NPASS   8                  // scatter passes (src-range partitions)
#define NPP     6250               // nodes per pass = N_NODES/NPASS
#define EB      (N_EDGES / 256)    // edge blocks per pass = 3125

// ---------------------------------------------------------------------------
// K1 (R10 design, measured good): classic LDS-tiled GEMM.
// 64x64 tile, thread = 4x4 sub-tile; As[k][r] pad 68; Ws[k][c] linear.
// Grid 782, LDS 49.5KB -> 3 blk/CU. R12 profile: dropped out of top-5
// (was 106us in the R5 lane=row design; lane-contiguous stores + LDS
// tiling fixed the 3.7x write amplification and 8.5% occupancy).
// ---------------------------------------------------------------------------
__global__ __launch_bounds__(256) void k_gemm_scores(
    const float* __restrict__ in, const float* __restrict__ W,
    const float* __restrict__ a, float* __restrict__ h,
    float* __restrict__ ssrc, float* __restrict__ sdst) {
  __shared__ float Ws[F_IN][F_OUT];     // 32 KB   [k][c]
  __shared__ float As[64][68];          // 17 KB   [k][r], +4 pad
  __shared__ float al[2 * F_OUT];

  const int tid  = threadIdx.x;
  const int row0 = blockIdx.x * 64;

  {
    const float4* Wg = reinterpret_cast<const float4*>(W);
    float4* Wl = reinterpret_cast<float4*>(&Ws[0][0]);
    #pragma unroll
    for (int i = 0; i < 8; ++i) Wl[tid + i * 256] = Wg[tid + i * 256];
  }
  if (tid < 2 * F_OUT) al[tid] = a[tid];

  const int rg = tid >> 4;              // 0..15 row group
  const int cg = tid & 15;              // 0..15 col group
  const int sr = tid >> 2;              // staging row 0..63
  const int sq = tid & 3;               // staging quad 0..3
  int grow = row0 + sr; if (grow >= N_NODES) grow = N_NODES - 1;

  float acc[4][4] = {{0.f}};

  for (int kc = 0; kc < 2; ++kc) {
    if (kc) __syncthreads();
    #pragma unroll
    for (int i = 0; i < 4; ++i) {
      const int slot = sq + 4 * i;
      const float4 v = *reinterpret_cast<const float4*>(
          in + (size_t)grow * F_IN + kc * 64 + slot * 4);
      As[slot * 4 + 0][sr] = v.x;
      As[slot * 4 + 1][sr] = v.y;
      As[slot * 4 + 2][sr] = v.z;
      As[slot * 4 + 3][sr] = v.w;
    }
    __syncthreads();

    #pragma unroll 8
    for (int kk = 0; kk < 64; ++kk) {
      const float4 av = *reinterpret_cast<const float4*>(&As[kk][rg * 4]);
      const float4 bv = *reinterpret_cast<const float4*>(&Ws[kc * 64 + kk][cg * 4]);
      acc[0][0] = fmaf(av.x, bv.x, acc[0][0]);
      acc[0][1] = fmaf(av.x, bv.y, acc[0][1]);
      acc[0][2] = fmaf(av.x, bv.z, acc[0][2]);
      acc[0][3] = fmaf(av.x, bv.w, acc[0][3]);
      acc[1][0] = fmaf(av.y, bv.x, acc[1][0]);
      acc[1][1] = fmaf(av.y, bv.y, acc[1][1]);
      acc[1][2] = fmaf(av.y, bv.z, acc[1][2]);
      acc[1][3] = fmaf(av.y, bv.w, acc[1][3]);
      acc[2][0] = fmaf(av.z, bv.x, acc[2][0]);
      acc[2][1] = fmaf(av.z, bv.y, acc[2][1]);
      acc[2][2] = fmaf(av.z, bv.z, acc[2][2]);
      acc[2][3] = fmaf(av.z, bv.w, acc[2][3]);
      acc[3][0] = fmaf(av.w, bv.x, acc[3][0]);
      acc[3][1] = fmaf(av.w, bv.y, acc[3][1]);
      acc[3][2] = fmaf(av.w, bv.z, acc[3][2]);
      acc[3][3] = fmaf(av.w, bv.w, acc[3][3]);
    }
  }

  #pragma unroll
  for (int i = 0; i < 4; ++i) {
    const int row = row0 + rg * 4 + i;
    if (row < N_NODES) {
      float4 hv = make_float4(acc[i][0], acc[i][1], acc[i][2], acc[i][3]);
      *reinterpret_cast<float4*>(h + (size_t)row * F_OUT + cg * 4) = hv;
    }
  }

  float ssr[4], sdr[4];
  #pragma unroll
  for (int i = 0; i < 4; ++i) {
    ssr[i] = acc[i][0] * al[cg * 4 + 0] + acc[i][1] * al[cg * 4 + 1]
           + acc[i][2] * al[cg * 4 + 2] + acc[i][3] * al[cg * 4 + 3];
    sdr[i] = acc[i][0] * al[F_OUT + cg * 4 + 0] + acc[i][1] * al[F_OUT + cg * 4 + 1]
           + acc[i][2] * al[F_OUT + cg * 4 + 2] + acc[i][3] * al[F_OUT + cg * 4 + 3];
  }
  #pragma unroll
  for (int m = 1; m < 16; m <<= 1) {
    #pragma unroll
    for (int i = 0; i < 4; ++i) {
      ssr[i] += __shfl_xor(ssr[i], m);
      sdr[i] += __shfl_xor(sdr[i], m);
    }
  }
  if (cg == 0) {
    #pragma unroll
    for (int i = 0; i < 4; ++i) {
      const int row = row0 + rg * 4 + i;
      if (row < N_NODES) { ssrc[row] = ssr[i]; sdst[row] = sdr[i]; }
    }
  }
}

// ---------------------------------------------------------------------------
// CSR build: histogram of src, 2-level exclusive scan, scatter {dst, ee}.
// ---------------------------------------------------------------------------
__global__ __launch_bounds__(256) void k_hist(const int* __restrict__ src,
                                              int* __restrict__ deg) {
  const int e = blockIdx.x * 256 + threadIdx.x;   // grid exact: 800000
  atomicAdd(&deg[src[e]], 1);
}

// per-block exclusive scan of 256 elements; bsum[b] = block total
__global__ __launch_bounds__(256) void k_scan_a(const int* __restrict__ deg,
                                                int* __restrict__ offs,
                                                int* __restrict__ bsum) {
  __shared__ int lds[256];
  const int i = blockIdx.x * 256 + threadIdx.x;   // deg zero-padded to NP
  const int v = deg[i];
  lds[threadIdx.x] = v;
  __syncthreads();
  #pragma unroll
  for (int off = 1; off < 256; off <<= 1) {
    int t = (threadIdx.x >= off) ? lds[threadIdx.x - off] : 0;
    __syncthreads();
    lds[threadIdx.x] += t;
    __syncthreads();
  }
  offs[i] = lds[threadIdx.x] - v;                 // exclusive within block
  if (threadIdx.x == 255) bsum[blockIdx.x] = lds[255];
}

// exclusive scan of the NB block sums (single block). bsum[NB..255] is
// POISON (0xAA) — guard the load.
__global__ __launch_bounds__(256) void k_scan_b(const int* __restrict__ bsum,
                                                int* __restrict__ boff) {
  __shared__ int lds[256];
  const int v = (threadIdx.x < NB) ? bsum[threadIdx.x] : 0;
  lds[threadIdx.x] = v;
  __syncthreads();
  #pragma unroll
  for (int off = 1; off < 256; off <<= 1) {
    int t = (threadIdx.x >= off) ? lds[threadIdx.x - off] : 0;
    __syncthreads();
    lds[threadIdx.x] += t;
    __syncthreads();
  }
  boff[threadIdx.x] = lds[threadIdx.x] - v;
}

// ---------------------------------------------------------------------------
// R12: pass-partitioned scatter (MSD counting-sort pass). Diagnosis:
// random 8B stores over the whole 6.4MB pairs arena -> every store dirtied
// a 64B line evicted partially-filled: WRITE_SIZE 53.3MB vs 6.4 useful
// (8.3x), FETCH 7.1MB = RMW line fetches, 46us at 1.3TB/s random-access.
// Fix: 8 passes, pass p scatters only src in [p*6250,(p+1)*6250) -> writes
// confined to ~800KB slice, lines fill while L2-resident, written back
// once. Blocks pass-major so passes run ~sequentially (order affects only
// speed, not correctness). src re-read x8 = 25.6MB, L3-resident.
// ---------------------------------------------------------------------------
__global__ __launch_bounds__(256) void k_scatter(
    const int* __restrict__ src, const int* __restrict__ dst,
    const float* __restrict__ adj,
    const float* __restrict__ ssrc, const float* __restrict__ sdst,
    const int* __restrict__ offs, const int* __restrict__ boff,
    int* __restrict__ cursor, int2* __restrict__ pairs) {
  const int pass = blockIdx.x / EB;               // 0..NPASS-1
  const int e = (blockIdx.x - pass * EB) * 256 + threadIdx.x;
  const int s = src[e];
  if ((unsigned)(s - pass * NPP) >= NPP) return;  // not my pass
  const int d = dst[e];
  const float sc = ssrc[s] + sdst[d];
  const float lr = sc > 0.f ? sc : ALPHA * sc;
  const float ee = expf(-lr) * adj[e];
  const int base = offs[s] + boff[s >> 8];
  const int pos  = base + atomicAdd(&cursor[s], 1);
  pairs[pos] = make_int2(d, __float_as_int(ee));
}

// ---------------------------------------------------------------------------
// K4: per-node gather + divide + ELU (fused epilogue). Wave per node,
// lane = feature. 4-edge unroll for MLP.
// ---------------------------------------------------------------------------
__global__ __launch_bounds__(256) void k_gather(
    const int2* __restrict__ pairs, const int* __restrict__ offs,
    const int* __restrict__ boff, const float* __restrict__ h,
    float* __restrict__ out) {
  const int wave = threadIdx.x >> 6;
  const int lane = threadIdx.x & 63;
  const int node = blockIdx.x * 4 + wave;         // grid exact: 12500

  const int o0 = offs[node] + boff[node >> 8];
  const int o1 = offs[node + 1] + boff[(node + 1) >> 8];

  float acc = 0.f, rs = 0.f;
  int j = o0;
  for (; j + 3 < o1; j += 4) {
    const int2 p0 = pairs[j];
    const int2 p1 = pairs[j + 1];
    const int2 p2 = pairs[j + 2];
    const int2 p3 = pairs[j + 3];
    const float h0 = h[(size_t)p0.x * F_OUT + lane];
    const float h1 = h[(size_t)p1.x * F_OUT + lane];
    const float h2 = h[(size_t)p2.x * F_OUT + lane];
    const float h3 = h[(size_t)p3.x * F_OUT + lane];
    const float e0 = __int_as_float(p0.y);
    const float e1 = __int_as_float(p1.y);
    const float e2 = __int_as_float(p2.y);
    const float e3 = __int_as_float(p3.y);
    acc += e0 * h0; rs += e0;
    acc += e1 * h1; rs += e1;
    acc += e2 * h2; rs += e2;
    acc += e3 * h3; rs += e3;
  }
  for (; j < o1; ++j) {
    const int2 p = pairs[j];
    const float ee = __int_as_float(p.y);
    acc += ee * h[(size_t)p.x * F_OUT + lane];
    rs  += ee;
  }

  float v = acc / rs;                             // deg==0 -> NaN, matches ref
  v = v > 0.f ? v : expm1f(v);
  out[(size_t)node * F_OUT + lane] = v;
}

extern "C" void kernel_launch(void* const* d_in, const int* in_sizes, int n_in,
                              void* d_out, int out_size, void* d_ws, size_t ws_size,
                              hipStream_t stream) {
  const float* input = (const float*)d_in[0];
  const float* W     = (const float*)d_in[1];
  const float* a     = (const float*)d_in[2];
  const float* adj   = (const float*)d_in[3];
  const int*   ei    = (const int*)d_in[4];
  const int*   src   = ei;
  const int*   dst   = ei + N_EDGES;
  float* out = (float*)d_out;

  // ---- workspace layout (all regions 16B-aligned) ----
  float* h    = (float*)d_ws;                        // 3.2M floats (12.8 MB)
  float* ssrc = h + (size_t)N_NODES * F_OUT;         // 50000
  float* sdst = ssrc + N_NODES;                      // 50000
  int*   deg    = (int*)(sdst + N_NODES);            // NP ints (zeroed)
  int*   cursor = deg + NP;                          // NP ints (zeroed)
  int*   offs   = cursor + NP;                       // NP ints
  int*   bsum   = offs + NP;                         // 256 ints
  int*   boff   = bsum + 256;                        // 256 ints
  int2*  pairs  = (int2*)(boff + 256);               // 800000 int2 (6.4 MB)

  hipMemsetAsync(deg, 0, 2 * NP * sizeof(int), stream);  // deg + cursor

  k_hist   <<<N_EDGES / 256, 256, 0, stream>>>(src, deg);
  k_scan_a <<<NB, 256, 0, stream>>>(deg, offs, bsum);
  k_scan_b <<<1, 256, 0, stream>>>(bsum, boff);
  k_gemm_scores<<<(N_NODES + 63) / 64, 256, 0, stream>>>(input, W, a, h, ssrc, sdst);
  k_scatter<<<NPASS * EB, 256, 0, stream>>>(src, dst, adj, ssrc, sdst,
                                            offs, boff, cursor, pairs);
  k_gather <<<N_NODES / 4, 256, 0, stream>>>(pairs, offs, boff, h, out);
}

// Round 15
// 214.772 us; speedup vs baseline: 1.0289x; 1.0289x over previous
//
#include <hip/hip_runtime.h>
#include <math.h>

#define N_NODES 50000
#define N_EDGES 800000
#define F_IN    128
#define F_OUT   64
#define ALPHA   0.2f

#define NP      50176              // N_NODES padded to 196*256
#define NB      196                // scan blocks
#define NPASS   8                  // scatter passes = XCDs
#define NPP     6250               // nodes per pass = N_NODES/NPASS
#define EB      (N_EDGES / 256)    // edge blocks per pass = 3125

// ---------------------------------------------------------------------------
// K1 (R10 design, measured good): classic LDS-tiled GEMM.
// 64x64 tile, thread = 4x4 sub-tile; As[k][r] pad 68; Ws[k][c] linear.
// Grid 782, LDS 49.5KB -> 3 blk/CU. R12: dropped out of top-5.
// ---------------------------------------------------------------------------
__global__ __launch_bounds__(256) void k_gemm_scores(
    const float* __restrict__ in, const float* __restrict__ W,
    const float* __restrict__ a, float* __restrict__ h,
    float* __restrict__ ssrc, float* __restrict__ sdst) {
  __shared__ float Ws[F_IN][F_OUT];     // 32 KB   [k][c]
  __shared__ float As[64][68];          // 17 KB   [k][r], +4 pad
  __shared__ float al[2 * F_OUT];

  const int tid  = threadIdx.x;
  const int row0 = blockIdx.x * 64;

  {
    const float4* Wg = reinterpret_cast<const float4*>(W);
    float4* Wl = reinterpret_cast<float4*>(&Ws[0][0]);
    #pragma unroll
    for (int i = 0; i < 8; ++i) Wl[tid + i * 256] = Wg[tid + i * 256];
  }
  if (tid < 2 * F_OUT) al[tid] = a[tid];

  const int rg = tid >> 4;              // 0..15 row group
  const int cg = tid & 15;              // 0..15 col group
  const int sr = tid >> 2;              // staging row 0..63
  const int sq = tid & 3;               // staging quad 0..3
  int grow = row0 + sr; if (grow >= N_NODES) grow = N_NODES - 1;

  float acc[4][4] = {{0.f}};

  for (int kc = 0; kc < 2; ++kc) {
    if (kc) __syncthreads();
    #pragma unroll
    for (int i = 0; i < 4; ++i) {
      const int slot = sq + 4 * i;
      const float4 v = *reinterpret_cast<const float4*>(
          in + (size_t)grow * F_IN + kc * 64 + slot * 4);
      As[slot * 4 + 0][sr] = v.x;
      As[slot * 4 + 1][sr] = v.y;
      As[slot * 4 + 2][sr] = v.z;
      As[slot * 4 + 3][sr] = v.w;
    }
    __syncthreads();

    #pragma unroll 8
    for (int kk = 0; kk < 64; ++kk) {
      const float4 av = *reinterpret_cast<const float4*>(&As[kk][rg * 4]);
      const float4 bv = *reinterpret_cast<const float4*>(&Ws[kc * 64 + kk][cg * 4]);
      acc[0][0] = fmaf(av.x, bv.x, acc[0][0]);
      acc[0][1] = fmaf(av.x, bv.y, acc[0][1]);
      acc[0][2] = fmaf(av.x, bv.z, acc[0][2]);
      acc[0][3] = fmaf(av.x, bv.w, acc[0][3]);
      acc[1][0] = fmaf(av.y, bv.x, acc[1][0]);
      acc[1][1] = fmaf(av.y, bv.y, acc[1][1]);
      acc[1][2] = fmaf(av.y, bv.z, acc[1][2]);
      acc[1][3] = fmaf(av.y, bv.w, acc[1][3]);
      acc[2][0] = fmaf(av.z, bv.x, acc[2][0]);
      acc[2][1] = fmaf(av.z, bv.y, acc[2][1]);
      acc[2][2] = fmaf(av.z, bv.z, acc[2][2]);
      acc[2][3] = fmaf(av.z, bv.w, acc[2][3]);
      acc[3][0] = fmaf(av.w, bv.x, acc[3][0]);
      acc[3][1] = fmaf(av.w, bv.y, acc[3][1]);
      acc[3][2] = fmaf(av.w, bv.z, acc[3][2]);
      acc[3][3] = fmaf(av.w, bv.w, acc[3][3]);
    }
  }

  #pragma unroll
  for (int i = 0; i < 4; ++i) {
    const int row = row0 + rg * 4 + i;
    if (row < N_NODES) {
      float4 hv = make_float4(acc[i][0], acc[i][1], acc[i][2], acc[i][3]);
      *reinterpret_cast<float4*>(h + (size_t)row * F_OUT + cg * 4) = hv;
    }
  }

  float ssr[4], sdr[4];
  #pragma unroll
  for (int i = 0; i < 4; ++i) {
    ssr[i] = acc[i][0] * al[cg * 4 + 0] + acc[i][1] * al[cg * 4 + 1]
           + acc[i][2] * al[cg * 4 + 2] + acc[i][3] * al[cg * 4 + 3];
    sdr[i] = acc[i][0] * al[F_OUT + cg * 4 + 0] + acc[i][1] * al[F_OUT + cg * 4 + 1]
           + acc[i][2] * al[F_OUT + cg * 4 + 2] + acc[i][3] * al[F_OUT + cg * 4 + 3];
  }
  #pragma unroll
  for (int m = 1; m < 16; m <<= 1) {
    #pragma unroll
    for (int i = 0; i < 4; ++i) {
      ssr[i] += __shfl_xor(ssr[i], m);
      sdr[i] += __shfl_xor(sdr[i], m);
    }
  }
  if (cg == 0) {
    #pragma unroll
    for (int i = 0; i < 4; ++i) {
      const int row = row0 + rg * 4 + i;
      if (row < N_NODES) { ssrc[row] = ssr[i]; sdst[row] = sdr[i]; }
    }
  }
}

// ---------------------------------------------------------------------------
// CSR build: histogram of src, 2-level exclusive scan, scatter {dst, ee}.
// ---------------------------------------------------------------------------
__global__ __launch_bounds__(256) void k_hist(const int* __restrict__ src,
                                              int* __restrict__ deg) {
  const int e = blockIdx.x * 256 + threadIdx.x;   // grid exact: 800000
  atomicAdd(&deg[src[e]], 1);
}

// per-block exclusive scan of 256 elements; bsum[b] = block total
__global__ __launch_bounds__(256) void k_scan_a(const int* __restrict__ deg,
                                                int* __restrict__ offs,
                                                int* __restrict__ bsum) {
  __shared__ int lds[256];
  const int i = blockIdx.x * 256 + threadIdx.x;   // deg zero-padded to NP
  const int v = deg[i];
  lds[threadIdx.x] = v;
  __syncthreads();
  #pragma unroll
  for (int off = 1; off < 256; off <<= 1) {
    int t = (threadIdx.x >= off) ? lds[threadIdx.x - off] : 0;
    __syncthreads();
    lds[threadIdx.x] += t;
    __syncthreads();
  }
  offs[i] = lds[threadIdx.x] - v;                 // exclusive within block
  if (threadIdx.x == 255) bsum[blockIdx.x] = lds[255];
}

// exclusive scan of the NB block sums (single block). bsum[NB..255] is
// POISON (0xAA) — guard the load.
__global__ __launch_bounds__(256) void k_scan_b(const int* __restrict__ bsum,
                                                int* __restrict__ boff) {
  __shared__ int lds[256];
  const int v = (threadIdx.x < NB) ? bsum[threadIdx.x] : 0;
  lds[threadIdx.x] = v;
  __syncthreads();
  #pragma unroll
  for (int off = 1; off < 256; off <<= 1) {
    int t = (threadIdx.x >= off) ? lds[threadIdx.x - off] : 0;
    __syncthreads();
    lds[threadIdx.x] += t;
    __syncthreads();
  }
  boff[threadIdx.x] = lds[threadIdx.x] - v;
}

// ---------------------------------------------------------------------------
// R14 scatter: XCD-BOUND pass partition. R14 measured: pass-major block
// order did NOT reduce WRITE_SIZE (46.8MB) because consecutive blocks of a
// pass round-robin across the 8 non-coherent per-XCD L2s -> each L2 held
// sparse 8B fragments of the same pairs lines, evicted partial. Fix:
// pass = blockIdx % 8 = XCD id (blocks round-robin XCDs, m09), so pass p's
// ~800KB write slice is owned exclusively by XCD p's L2 (<4MB): lines fill
// fully before writeback. Passes run concurrently on disjoint XCDs; no
// dispatch-order assumption. Correctness pass-independent (disjoint src
// ranges -> disjoint cursor/pairs slots).
// ---------------------------------------------------------------------------
__global__ __launch_bounds__(256) void k_scatter(
    const int* __restrict__ src, const int* __restrict__ dst,
    const float* __restrict__ adj,
    const float* __restrict__ ssrc, const float* __restrict__ sdst,
    const int* __restrict__ offs, const int* __restrict__ boff,
    int* __restrict__ cursor, int2* __restrict__ pairs) {
  const int pass = blockIdx.x % NPASS;            // = XCD id (round-robin)
  const int e = (blockIdx.x / NPASS) * 256 + threadIdx.x;
  const int s = src[e];
  if ((unsigned)(s - pass * NPP) >= NPP) return;  // not my pass
  const int d = dst[e];
  const float sc = ssrc[s] + sdst[d];
  const float lr = sc > 0.f ? sc : ALPHA * sc;
  const float ee = expf(-lr) * adj[e];
  const int base = offs[s] + boff[s >> 8];
  const int pos  = base + atomicAdd(&cursor[s], 1);
  pairs[pos] = make_int2(d, __float_as_int(ee));
}

// ---------------------------------------------------------------------------
// K4: per-node gather + divide + ELU (fused epilogue). Wave per node,
// lane = feature. 4-edge unroll for MLP.
// ---------------------------------------------------------------------------
__global__ __launch_bounds__(256) void k_gather(
    const int2* __restrict__ pairs, const int* __restrict__ offs,
    const int* __restrict__ boff, const float* __restrict__ h,
    float* __restrict__ out) {
  const int wave = threadIdx.x >> 6;
  const int lane = threadIdx.x & 63;
  const int node = blockIdx.x * 4 + wave;         // grid exact: 12500

  const int o0 = offs[node] + boff[node >> 8];
  const int o1 = offs[node + 1] + boff[(node + 1) >> 8];

  float acc = 0.f, rs = 0.f;
  int j = o0;
  for (; j + 3 < o1; j += 4) {
    const int2 p0 = pairs[j];
    const int2 p1 = pairs[j + 1];
    const int2 p2 = pairs[j + 2];
    const int2 p3 = pairs[j + 3];
    const float h0 = h[(size_t)p0.x * F_OUT + lane];
    const float h1 = h[(size_t)p1.x * F_OUT + lane];
    const float h2 = h[(size_t)p2.x * F_OUT + lane];
    const float h3 = h[(size_t)p3.x * F_OUT + lane];
    const float e0 = __int_as_float(p0.y);
    const float e1 = __int_as_float(p1.y);
    const float e2 = __int_as_float(p2.y);
    const float e3 = __int_as_float(p3.y);
    acc += e0 * h0; rs += e0;
    acc += e1 * h1; rs += e1;
    acc += e2 * h2; rs += e2;
    acc += e3 * h3; rs += e3;
  }
  for (; j < o1; ++j) {
    const int2 p = pairs[j];
    const float ee = __int_as_float(p.y);
    acc += ee * h[(size_t)p.x * F_OUT + lane];
    rs  += ee;
  }

  float v = acc / rs;                             // deg==0 -> NaN, matches ref
  v = v > 0.f ? v : expm1f(v);
  out[(size_t)node * F_OUT + lane] = v;
}

extern "C" void kernel_launch(void* const* d_in, const int* in_sizes, int n_in,
                              void* d_out, int out_size, void* d_ws, size_t ws_size,
                              hipStream_t stream) {
  const float* input = (const float*)d_in[0];
  const float* W     = (const float*)d_in[1];
  const float* a     = (const float*)d_in[2];
  const float* adj   = (const float*)d_in[3];
  const int*   ei    = (const int*)d_in[4];
  const int*   src   = ei;
  const int*   dst   = ei + N_EDGES;
  float* out = (float*)d_out;

  // ---- workspace layout (all regions 16B-aligned) ----
  float* h    = (float*)d_ws;                        // 3.2M floats (12.8 MB)
  float* ssrc = h + (size_t)N_NODES * F_OUT;         // 50000
  float* sdst = ssrc + N_NODES;                      // 50000
  int*   deg    = (int*)(sdst + N_NODES);            // NP ints (zeroed)
  int*   cursor = deg + NP;                          // NP ints (zeroed)
  int*   offs   = cursor + NP;                       // NP ints
  int*   bsum   = offs + NP;                         // 256 ints
  int*   boff   = bsum + 256;                        // 256 ints
  int2*  pairs  = (int2*)(boff + 256);               // 800000 int2 (6.4 MB)

  hipMemsetAsync(deg, 0, 2 * NP * sizeof(int), stream);  // deg + cursor

  k_hist   <<<N_EDGES / 256, 256, 0, stream>>>(src, deg);
  k_scan_a <<<NB, 256, 0, stream>>>(deg, offs, bsum);
  k_scan_b <<<1, 256, 0, stream>>>(bsum, boff);
  k_gemm_scores<<<(N_NODES + 63) / 64, 256, 0, stream>>>(input, W, a, h, ssrc, sdst);
  k_scatter<<<NPASS * EB, 256, 0, stream>>>(src, dst, adj, ssrc, sdst,
                                            offs, boff, cursor, pairs);
  k_gather <<<N_NODES / 4, 256, 0, stream>>>(pairs, offs, boff, h, out);
}